// Round 6
// baseline (1692.858 us; speedup 1.0000x reference)
//
#include <hip/hip_runtime.h>
#include <math.h>

#define EMB 768
#define NH 12
#define HD 64
#define NL 12
#define NV 50257
#define MAXS 1024
#define S_PAST 1023
#define E3 2304
#define E4 3072

typedef unsigned int u32;

// KV copy queue: 2 arrays x 2,359,296 float4; tile = 512 float4 (8KB)
#define KV_F4 2359296u
#define TILE_F4 512u
#define HALF_TILES 4608u
#define NTILES 9216u

// workspace layout, u32 word indices (first 2048 words memset to 0 each call)
#define WI_TICKET 0
#define WI_CNT(l,k) (32 + ((l)*3 + (k)) * 16)
#define WI_REL(l,k) (1024 + ((l)*3 + (k)) * 16)
// float offsets (words)
#define WF_H    2048
#define WF_QKV  (WF_H + EMB)
#define WF_FC   (WF_QKV + E3)
#define WF_PART (WF_FC + E4)    // 192 * 68 floats

struct CopyCtx {
  const float4* pk4; const float4* pv4;
  float4* opk4; float4* opv4; u32* ticket;
};

__device__ __forceinline__ void copy_tile(const CopyCtx& cc, u32 t) {
  bool isv = t >= HALF_TILES;
  u32 tt = isv ? t - HALF_TILES : t;
  const float4* src = isv ? cc.pv4 : cc.pk4;
  float4* dst = isv ? cc.opv4 : cc.opk4;
  u32 base = tt * TILE_F4 + threadIdx.x;
#pragma unroll
  for (int i = 0; i < 2; i++) {
    u32 idx = base + i * 256;
    u32 row = (idx >> 4) & (MAXS - 1);
    float4 v = src[idx];
    if (row != S_PAST) dst[idx] = v;   // slot S_PAST is written by attn (new k/v)
  }
}

// wait for *rel != 0; while waiting, pull KV-copy tiles (idle work instead of sleep)
__device__ __forceinline__ void wait_rel(u32* rel, const CopyCtx& cc, u32* sscr) {
  bool qdone = false;
  while (true) {
    if (threadIdx.x == 0)
      sscr[0] = __hip_atomic_load(rel, __ATOMIC_ACQUIRE, __HIP_MEMORY_SCOPE_AGENT);
    __syncthreads();
    u32 f = sscr[0];
    __syncthreads();
    if (f) break;
    if (!qdone) {
      if (threadIdx.x == 0) sscr[1] = atomicAdd(cc.ticket, 1u);
      __syncthreads();
      u32 t = sscr[1];
      __syncthreads();
      if (t < NTILES) copy_tile(cc, t); else qdone = true;
    } else {
      __builtin_amdgcn_s_sleep(8);
    }
  }
}

// producer completion: arrival counter + write-once release flag
__device__ __forceinline__ void signal(u32* cnt, u32* rel, u32 n) {
  __syncthreads();
  __threadfence();
  if (threadIdx.x == 0) {
    u32 old = atomicAdd(cnt, 1u);
    if (old == n - 1)
      __hip_atomic_store(rel, 1u, __ATOMIC_RELEASE, __HIP_MEMORY_SCOPE_AGENT);
  }
}

__device__ __forceinline__ void blockReduce2(float& a, float& b, volatile float* ra, volatile float* rb) {
  int lane = threadIdx.x & 63, wid = threadIdx.x >> 6;
#pragma unroll
  for (int o = 32; o > 0; o >>= 1) { a += __shfl_down(a, o); b += __shfl_down(b, o); }
  if (lane == 0) { ra[wid] = a; rb[wid] = b; }
  __syncthreads();
  if (threadIdx.x == 0) {
    ra[0] = ra[0] + ra[1] + ra[2] + ra[3];
    rb[0] = rb[0] + rb[1] + rb[2] + rb[3];
  }
  __syncthreads();
  a = ra[0]; b = rb[0];
}

__device__ __forceinline__ float gelu(float x) {
  return 0.5f * x * (1.f + tanhf(0.7978845608028654f * (x + 0.044715f * x * x * x)));
}

// 48 rows x 256 cols LN-GEMV tile; out += xs @ W
__device__ void phase_ln_gemv48(int et, int jt, const float* __restrict__ hvec,
                                const float* __restrict__ g, const float* __restrict__ bb,
                                const float* __restrict__ W, float* __restrict__ out,
                                int N, int l, float* smem) {
  float* lh = smem;
  float* xs = smem + 768;
  volatile float* ra = smem + 816;
  volatile float* rb = smem + 820;
  float4* red = (float4*)(smem + 832);
  int tid = threadIdx.x, lane = tid & 63, wid = tid >> 6;
  float s1 = 0.f, s2 = 0.f;
  for (int e = tid; e < EMB; e += 256) { float v = hvec[e]; lh[e] = v; s1 += v; s2 += v * v; }
  blockReduce2(s1, s2, ra, rb);
  float mean = s1 * (1.f / EMB);
  float var = s2 * (1.f / EMB) - mean * mean;
  float rstd = rsqrtf(var + 1e-5f);
  int e0 = et * 48;
  if (tid < 48) {
    int e = e0 + tid;
    xs[tid] = (lh[e] - mean) * rstd * g[l * EMB + e] + bb[l * EMB + e];
  }
  __syncthreads();
  int j4 = jt * 64 + lane;
  int N4 = N >> 2;
  const float4* p = (const float4*)(W + (size_t)l * EMB * N) + (size_t)(e0 + wid) * N4 + j4;
  float4 w[12];
#pragma unroll
  for (int i = 0; i < 12; i++) w[i] = p[(size_t)(i * 4) * N4];
  float4 acc = {0.f, 0.f, 0.f, 0.f};
#pragma unroll
  for (int i = 0; i < 12; i++) {
    float x = xs[wid + i * 4];
    acc.x += x * w[i].x; acc.y += x * w[i].y; acc.z += x * w[i].z; acc.w += x * w[i].w;
  }
  red[wid * 64 + lane] = acc;
  __syncthreads();
  if (wid == 0) {
    float4 a0 = red[lane], a1 = red[64 + lane], a2 = red[128 + lane], a3 = red[192 + lane];
    float rx = a0.x + a1.x + a2.x + a3.x;
    float ry = a0.y + a1.y + a2.y + a3.y;
    float rz = a0.z + a1.z + a2.z + a3.z;
    float rw = a0.w + a1.w + a2.w + a3.w;
    float* op = out + (size_t)j4 * 4;
    atomicAdd(op + 0, rx); atomicAdd(op + 1, ry);
    atomicAdd(op + 2, rz); atomicAdd(op + 3, rw);
  }
}

// attention partials for (head h, 64-key chunk c); chunk 15 writes the new K/V slot
__device__ void phase_attn(int h, int c, const float* __restrict__ qkv,
                           const float* __restrict__ pk, const float* __restrict__ pv,
                           const float* __restrict__ mask, float* __restrict__ opk,
                           float* __restrict__ opv, float* __restrict__ part,
                           int l, float* smem) {
  float4* qs4 = (float4*)smem;            // 16 float4
  float* sc = smem + 64;                  // 64
  float4* redo = (float4*)(smem + 128);   // 64 float4
  int tid = threadIdx.x, lane = tid & 63, wid = tid >> 6;
  int sub = tid & 15, grp = tid >> 4;
  if (tid < 16) qs4[tid] = ((const float4*)(qkv + h * 64))[tid];
  __syncthreads();
  size_t base = ((size_t)(l * NH + h) * MAXS) * HD;
  const float4* K4 = (const float4*)(pk + base);
  const float4* V4 = (const float4*)(pv + base);
  int t0 = c * 64;
  float4 kreg[4];
#pragma unroll
  for (int i = 0; i < 4; i++) {
    int t = t0 + grp + i * 16;
    kreg[i] = (t == S_PAST) ? ((const float4*)(qkv + EMB + h * 64))[sub] : K4[(size_t)t * 16 + sub];
  }
  if (c == 15 && grp == 15)
    ((float4*)(opk + base))[(size_t)S_PAST * 16 + sub] = kreg[3];
  float4 q4 = qs4[sub];
#pragma unroll
  for (int i = 0; i < 4; i++) {
    int key = grp + i * 16;
    float p = q4.x * kreg[i].x + q4.y * kreg[i].y + q4.z * kreg[i].z + q4.w * kreg[i].w;
    p += __shfl_xor(p, 1); p += __shfl_xor(p, 2);
    p += __shfl_xor(p, 4); p += __shfl_xor(p, 8);
    if (sub == 0) sc[key] = p * 0.125f + (1.f - mask[t0 + key]) * (-1e9f);
  }
  __syncthreads();
  if (wid == 0) {
    float a = sc[lane];
    float m = a;
#pragma unroll
    for (int o = 32; o > 0; o >>= 1) m = fmaxf(m, __shfl_down(m, o));
    m = __shfl(m, 0);
    float ea = expf(a - m);
    sc[lane] = ea;
    float s = ea;
#pragma unroll
    for (int o = 32; o > 0; o >>= 1) s += __shfl_down(s, o);
    if (lane == 0) { part[(h * 16 + c) * 68 + 0] = m; part[(h * 16 + c) * 68 + 1] = s; }
  }
  __syncthreads();
  float4 vreg[4];
#pragma unroll
  for (int i = 0; i < 4; i++) {
    int t = t0 + grp + i * 16;
    vreg[i] = (t == S_PAST) ? ((const float4*)(qkv + 2 * EMB + h * 64))[sub] : V4[(size_t)t * 16 + sub];
  }
  if (c == 15 && grp == 15)
    ((float4*)(opv + base))[(size_t)S_PAST * 16 + sub] = vreg[3];
  float4 acc = {0.f, 0.f, 0.f, 0.f};
#pragma unroll
  for (int i = 0; i < 4; i++) {
    float w = sc[grp + i * 16];
    acc.x += w * vreg[i].x; acc.y += w * vreg[i].y; acc.z += w * vreg[i].z; acc.w += w * vreg[i].w;
  }
  acc.x += __shfl_xor(acc.x, 16); acc.y += __shfl_xor(acc.y, 16);
  acc.z += __shfl_xor(acc.z, 16); acc.w += __shfl_xor(acc.w, 16);
  acc.x += __shfl_xor(acc.x, 32); acc.y += __shfl_xor(acc.y, 32);
  acc.z += __shfl_xor(acc.z, 32); acc.w += __shfl_xor(acc.w, 32);
  if (lane < 16) redo[wid * 16 + lane] = acc;
  __syncthreads();
  if (tid < 16) {
    float4 a0 = redo[tid], a1 = redo[16 + tid], a2 = redo[32 + tid], a3 = redo[48 + tid];
    float4 r;
    r.x = a0.x + a1.x + a2.x + a3.x;
    r.y = a0.y + a1.y + a2.y + a3.y;
    r.z = a0.z + a1.z + a2.z + a3.z;
    r.w = a0.w + a1.w + a2.w + a3.w;
    ((float4*)(part + (h * 16 + c) * 68 + 4))[tid] = r;
  }
}

// combine 16 chunk-partials for a 16-dim slice of head, then 16-row GEMV into h
__device__ void phase_proj(int rt, int jb, const float* __restrict__ part,
                           const float* __restrict__ W, const float* __restrict__ bias,
                           float* __restrict__ hout, int l, float* smem) {
  int h = rt >> 2, esub = rt & 3;
  float* xs = smem;
  float4* red = (float4*)(smem + 16);
  int tid = threadIdx.x, lane = tid & 63, wid = tid >> 6;
  if (tid < 16) {
    float M = -1e30f;
#pragma unroll
    for (int q = 0; q < 16; q++) M = fmaxf(M, part[(h * 16 + q) * 68]);
    float T = 0.f, o = 0.f;
    int d = esub * 16 + tid;
#pragma unroll
    for (int q = 0; q < 16; q++) {
      float w = expf(part[(h * 16 + q) * 68] - M);
      T += part[(h * 16 + q) * 68 + 1] * w;
      o += part[(h * 16 + q) * 68 + 4 + d] * w;
    }
    xs[tid] = o / T;
  }
  __syncthreads();
  int j4 = jb * 64 + lane;
  const int N4 = EMB >> 2;
  int r0 = h * 64 + esub * 16;
  const float4* p = (const float4*)(W + (size_t)l * EMB * EMB) + (size_t)(r0 + wid) * N4 + j4;
  float4 w[4];
#pragma unroll
  for (int i = 0; i < 4; i++) w[i] = p[(size_t)(i * 4) * N4];
  float4 acc = {0.f, 0.f, 0.f, 0.f};
#pragma unroll
  for (int i = 0; i < 4; i++) {
    float x = xs[wid + i * 4];
    acc.x += x * w[i].x; acc.y += x * w[i].y; acc.z += x * w[i].z; acc.w += x * w[i].w;
  }
  red[wid * 64 + lane] = acc;
  __syncthreads();
  if (wid == 0) {
    float4 a0 = red[lane], a1 = red[64 + lane], a2 = red[128 + lane], a3 = red[192 + lane];
    float rx = a0.x + a1.x + a2.x + a3.x;
    float ry = a0.y + a1.y + a2.y + a3.y;
    float rz = a0.z + a1.z + a2.z + a3.z;
    float rw = a0.w + a1.w + a2.w + a3.w;
    if (rt == 0) {
      const float* bp = bias + l * EMB + jb * 256 + lane * 4;
      rx += bp[0]; ry += bp[1]; rz += bp[2]; rw += bp[3];
    }
    float* op = hout + (size_t)jb * 256 + (size_t)lane * 4;
    atomicAdd(op + 0, rx); atomicAdd(op + 1, ry);
    atomicAdd(op + 2, rz); atomicAdd(op + 3, rw);
  }
}

// 64 gelu rows x 256 cols into h
__device__ void phase_mlp(int etile, int jb, const float* __restrict__ fcv,
                          const float* __restrict__ W, const float* __restrict__ bias,
                          float* __restrict__ hout, int l, float* smem) {
  float* xs = smem;
  float4* red = (float4*)(smem + 64);
  int tid = threadIdx.x, lane = tid & 63, wid = tid >> 6;
  int e0 = etile * 64;
  if (tid < 64) xs[tid] = gelu(fcv[e0 + tid]);
  __syncthreads();
  int j4 = jb * 64 + lane;
  const int N4 = EMB >> 2;
  const float4* p = (const float4*)(W + (size_t)l * E4 * EMB) + (size_t)(e0 + wid) * N4 + j4;
  float4 w[16];
#pragma unroll
  for (int i = 0; i < 16; i++) w[i] = p[(size_t)(i * 4) * N4];
  float4 acc = {0.f, 0.f, 0.f, 0.f};
#pragma unroll
  for (int i = 0; i < 16; i++) {
    float x = xs[wid + i * 4];
    acc.x += x * w[i].x; acc.y += x * w[i].y; acc.z += x * w[i].z; acc.w += x * w[i].w;
  }
  red[wid * 64 + lane] = acc;
  __syncthreads();
  if (wid == 0) {
    float4 a0 = red[lane], a1 = red[64 + lane], a2 = red[128 + lane], a3 = red[192 + lane];
    float rx = a0.x + a1.x + a2.x + a3.x;
    float ry = a0.y + a1.y + a2.y + a3.y;
    float rz = a0.z + a1.z + a2.z + a3.z;
    float rw = a0.w + a1.w + a2.w + a3.w;
    if (etile == 0) {
      const float* bp = bias + l * EMB + j4 * 4;
      rx += bp[0]; ry += bp[1]; rz += bp[2]; rw += bp[3];
    }
    float* op = hout + (size_t)j4 * 4;
    atomicAdd(op + 0, rx); atomicAdd(op + 1, ry);
    atomicAdd(op + 2, rz); atomicAdd(op + 3, rw);
  }
}

// h = wte[id] + wpe[S_PAST]; seed layer-0 qkv bias
__global__ __launch_bounds__(256) void init_kernel(
    const int* __restrict__ ids, const float* __restrict__ wte,
    const float* __restrict__ wpe, const float* __restrict__ attn_b,
    float* __restrict__ wsf) {
  int idx = blockIdx.x * 256 + threadIdx.x;
  float* h = wsf + WF_H;
  float* qkv = wsf + WF_QKV;
  if (idx < E3) qkv[idx] = attn_b[idx];
  if (idx < EMB) {
    int id = ids[0];
    h[idx] = wte[(size_t)id * EMB + idx] + wpe[(size_t)S_PAST * EMB + idx];
  }
}

// K1: qkv-GEMV (144) -> attn (192) -> proj (144), flag-chained; waiters pull KV tiles
__global__ __launch_bounds__(256) void k1_qkv_attn_proj(
    const float* __restrict__ pk, const float* __restrict__ pv,
    const float* __restrict__ mask,
    const float* __restrict__ ln1_g, const float* __restrict__ ln1_b,
    const float* __restrict__ attn_w, const float* __restrict__ proj_w,
    const float* __restrict__ proj_b, const float* __restrict__ fc_b,
    float* __restrict__ opk, float* __restrict__ opv,
    float* __restrict__ wsf, int l) {
  __shared__ __align__(16) float smem[1856];
  __shared__ u32 sscr[2];
  u32* wsu = (u32*)wsf;
  float* wh = wsf + WF_H;
  float* wqkv = wsf + WF_QKV;
  float* wfc = wsf + WF_FC;
  float* wpart = wsf + WF_PART;
  CopyCtx cc = {(const float4*)pk, (const float4*)pv, (float4*)opk, (float4*)opv, wsu + WI_TICKET};
  int bi = blockIdx.x, tid = threadIdx.x;
  if (bi < 144) {
    phase_ln_gemv48(bi / 9, bi % 9, wh, ln1_g, ln1_b, attn_w, wqkv, E3, l, smem);
    signal(wsu + WI_CNT(l, 0), wsu + WI_REL(l, 0), 144);
    wait_rel(wsu + WI_REL(l, 1), cc, sscr);   // drain copy tiles during attn phase
  } else if (bi < 336) {
    wait_rel(wsu + WI_REL(l, 0), cc, sscr);
    int ai = bi - 144;
    phase_attn(ai >> 4, ai & 15, wqkv, pk, pv, mask, opk, opv, wpart, l, smem);
    signal(wsu + WI_CNT(l, 1), wsu + WI_REL(l, 1), 192);
  } else {
    int pi = bi - 336;
    if (pi < 12) wfc[pi * 256 + tid] = fc_b[l * E4 + pi * 256 + tid];  // seed fc bias
    wait_rel(wsu + WI_REL(l, 1), cc, sscr);
    phase_proj(pi / 3, pi % 3, wpart, proj_w, proj_b, wh, l, smem);
  }
}

// K2: fc-GEMV (192) -> mlp (144), flag-chained
__global__ __launch_bounds__(256) void k2_fc_mlp(
    const float* __restrict__ pk, const float* __restrict__ pv,
    const float* __restrict__ ln2_g, const float* __restrict__ ln2_b,
    const float* __restrict__ fc_w, const float* __restrict__ mlp_w,
    const float* __restrict__ mlp_b, const float* __restrict__ attn_b,
    float* __restrict__ opk, float* __restrict__ opv,
    float* __restrict__ wsf, int l) {
  __shared__ __align__(16) float smem[1856];
  __shared__ u32 sscr[2];
  u32* wsu = (u32*)wsf;
  float* wh = wsf + WF_H;
  float* wqkv = wsf + WF_QKV;
  float* wfc = wsf + WF_FC;
  CopyCtx cc = {(const float4*)pk, (const float4*)pv, (float4*)opk, (float4*)opv, wsu + WI_TICKET};
  int bi = blockIdx.x, tid = threadIdx.x;
  if (bi < 192) {
    phase_ln_gemv48(bi / 12, bi % 12, wh, ln2_g, ln2_b, fc_w, wfc, E4, l, smem);
    signal(wsu + WI_CNT(l, 2), wsu + WI_REL(l, 2), 192);
  } else {
    int ei = bi - 192;
    if (l + 1 < NL && ei < 9)   // seed next layer's qkv bias
      wqkv[ei * 256 + tid] = attn_b[(l + 1) * E3 + ei * 256 + tid];
    wait_rel(wsu + WI_REL(l, 2), cc, sscr);
    phase_mlp(ei / 3, ei % 3, wfc, mlp_w, mlp_b, wh, l, smem);
  }
}

// final LN + logits; then drain any remaining KV-copy tiles
__global__ __launch_bounds__(256) void logits_lnf_drain(
    const float* __restrict__ g, const float* __restrict__ b,
    const float* __restrict__ wte, float* __restrict__ out,
    const float* __restrict__ pk, const float* __restrict__ pv,
    float* __restrict__ opk, float* __restrict__ opv,
    float* __restrict__ wsf) {
  __shared__ __align__(16) float4 xs4[192];
  __shared__ float ra[4], rb[4];
  __shared__ u32 sscr[2];
  u32* wsu = (u32*)wsf;
  const float* hvec = wsf + WF_H;
  CopyCtx cc = {(const float4*)pk, (const float4*)pv, (float4*)opk, (float4*)opv, wsu + WI_TICKET};
  int tid = threadIdx.x, lane = tid & 63, wid = tid >> 6;
  float s1 = 0.f, s2 = 0.f;
  float v0[3];
  int k = 0;
  for (int e = tid; e < EMB; e += 256, k++) { float v = hvec[e]; v0[k] = v; s1 += v; s2 += v * v; }
  blockReduce2(s1, s2, ra, rb);
  float mean = s1 * (1.f / EMB);
  float var = s2 * (1.f / EMB) - mean * mean;
  float rstd = rsqrtf(var + 1e-5f);
  k = 0;
  for (int e = tid; e < EMB; e += 256, k++)
    ((float*)xs4)[e] = (v0[k] - mean) * rstd * g[e] + b[e];
  __syncthreads();
  int v = blockIdx.x * 4 + wid;
  if (v < NV) {
    const float4* row = (const float4*)(wte + (size_t)v * EMB);
    float4 a0 = row[lane], a1 = row[lane + 64], a2 = row[lane + 128];
    float4 x0 = xs4[lane], x1 = xs4[lane + 64], x2 = xs4[lane + 128];
    float acc = a0.x * x0.x + a0.y * x0.y + a0.z * x0.z + a0.w * x0.w
              + a1.x * x1.x + a1.y * x1.y + a1.z * x1.z + a1.w * x1.w
              + a2.x * x2.x + a2.y * x2.y + a2.z * x2.z + a2.w * x2.w;
#pragma unroll
    for (int o = 32; o > 0; o >>= 1) acc += __shfl_down(acc, o);
    if (lane == 0) out[v] = acc;
  }
  // drain residual copy tiles (cheap pre-check avoids ticket storms when empty)
  if (tid == 0) sscr[0] = __hip_atomic_load(cc.ticket, __ATOMIC_RELAXED, __HIP_MEMORY_SCOPE_AGENT);
  __syncthreads();
  if (sscr[0] < NTILES) {
    bool qdone = false;
    while (!qdone) {
      if (tid == 0) sscr[1] = atomicAdd(cc.ticket, 1u);
      __syncthreads();
      u32 t = sscr[1];
      __syncthreads();
      if (t < NTILES) copy_tile(cc, t); else qdone = true;
    }
  }
}

extern "C" void kernel_launch(void* const* d_in, const int* in_sizes, int n_in,
                              void* d_out, int out_size, void* d_ws, size_t ws_size,
                              hipStream_t stream) {
  const int* input_ids = (const int*)d_in[0];
  const float* past_key = (const float*)d_in[1];
  const float* past_value = (const float*)d_in[2];
  const float* mask = (const float*)d_in[4];
  const float* wte = (const float*)d_in[5];
  const float* wpe = (const float*)d_in[6];
  const float* ln1_g = (const float*)d_in[7];
  const float* ln1_b = (const float*)d_in[8];
  const float* attn_w = (const float*)d_in[9];
  const float* attn_b = (const float*)d_in[10];
  const float* proj_w = (const float*)d_in[11];
  const float* proj_b = (const float*)d_in[12];
  const float* ln2_g = (const float*)d_in[13];
  const float* ln2_b = (const float*)d_in[14];
  const float* fc_w = (const float*)d_in[15];
  const float* fc_b = (const float*)d_in[16];
  const float* mlp_w = (const float*)d_in[17];
  const float* mlp_b = (const float*)d_in[18];
  const float* lnf_g = (const float*)d_in[19];
  const float* lnf_b = (const float*)d_in[20];

  float* out = (float*)d_out;
  float* out_logits = out;
  float* out_pk = out + NV;
  float* out_pv = out_pk + (size_t)NL * NH * MAXS * HD;
  float* wsf = (float*)d_ws;

  // zero ticket + counters + release flags (graph-captured memset node)
  hipMemsetAsync(d_ws, 0, 8192, stream);
  init_kernel<<<9, 256, 0, stream>>>(input_ids, wte, wpe, attn_b, wsf);

  for (int l = 0; l < NL; l++) {
    k1_qkv_attn_proj<<<480, 256, 0, stream>>>(past_key, past_value, mask,
        ln1_g, ln1_b, attn_w, proj_w, proj_b, fc_b, out_pk, out_pv, wsf, l);
    k2_fc_mlp<<<336, 256, 0, stream>>>(past_key, past_value,
        ln2_g, ln2_b, fc_w, mlp_w, mlp_b, attn_b, out_pk, out_pv, wsf, l);
  }
  logits_lnf_drain<<<12565, 256, 0, stream>>>(lnf_g, lnf_b, wte, out_logits,
      past_key, past_value, out_pk, out_pv, wsf);
}

// Round 7
// 448.522 us; speedup vs baseline: 3.7743x; 3.7743x over previous
//
#include <hip/hip_runtime.h>
#include <math.h>

#define EMB 768
#define NH 12
#define HD 64
#define NL 12
#define NV 50257
#define MAXS 1024
#define S_PAST 1023
#define E3 2304
#define E4 3072

// workspace float offsets
#define WS_H    0
#define WS_QKV  768
#define WS_FC   3072
#define WS_PART 6144   // 192 entries * 68 floats

__device__ __forceinline__ void blockReduce2(float& a, float& b, volatile float* ra, volatile float* rb) {
  int lane = threadIdx.x & 63, wid = threadIdx.x >> 6;
#pragma unroll
  for (int o = 32; o > 0; o >>= 1) { a += __shfl_down(a, o); b += __shfl_down(b, o); }
  if (lane == 0) { ra[wid] = a; rb[wid] = b; }
  __syncthreads();
  if (threadIdx.x == 0) {
    ra[0] = ra[0] + ra[1] + ra[2] + ra[3];
    rb[0] = rb[0] + rb[1] + rb[2] + rb[3];
  }
  __syncthreads();
  a = ra[0]; b = rb[0];
}

// h = wte[id] + wpe[S]; seed layer-0 qkv with attn_b
__global__ void init_kernel(const int* __restrict__ ids, const float* __restrict__ wte,
                            const float* __restrict__ wpe, const float* __restrict__ attn_b,
                            float* __restrict__ hvec, float* __restrict__ qkv) {
  int idx = blockIdx.x * 256 + threadIdx.x;
  if (idx < E3) qkv[idx] = attn_b[idx];
  if (idx < EMB) {
    int id = ids[0];
    hvec[idx] = wte[(size_t)id * EMB + idx] + wpe[(size_t)S_PAST * EMB + idx];
  }
}

// out[j] += sum_e LN(h)[e] * W[l][e][j]; 32 rows x 256 cols per block.
// Weight loads issued BEFORE the LN reduction so stats latency hides under them.
__global__ void ln_gemv4(const float* __restrict__ hvec, const float* __restrict__ g,
                         const float* __restrict__ bb, const float* __restrict__ W,
                         float* __restrict__ out, int N, int l) {
  __shared__ float lh[EMB];
  __shared__ float xs[32];
  __shared__ float ra[4], rb[4];
  __shared__ float4 red[4][64];
  int tid = threadIdx.x, lane = tid & 63, wid = tid >> 6;
  int e0 = blockIdx.y * 32;
  // issue h loads (oldest -> stats can wait on these alone)
  float hv0 = hvec[tid], hv1 = hvec[tid + 256], hv2 = hvec[tid + 512];
  // issue weight loads (stay in flight during LN)
  int j4 = blockIdx.x * 64 + lane;
  int N4 = N >> 2;
  const float4* p = (const float4*)(W + (size_t)l * EMB * N) + (size_t)(e0 + wid) * N4 + j4;
  float4 w[8];
#pragma unroll
  for (int i = 0; i < 8; i++) w[i] = p[(size_t)(i * 4) * N4];
  float gv = 0.f, bv = 0.f;
  if (tid < 32) { gv = g[l * EMB + e0 + tid]; bv = bb[l * EMB + e0 + tid]; }
  // LN stats
  lh[tid] = hv0; lh[tid + 256] = hv1; lh[tid + 512] = hv2;
  float s1 = hv0 + hv1 + hv2;
  float s2 = hv0 * hv0 + hv1 * hv1 + hv2 * hv2;
  blockReduce2(s1, s2, ra, rb);
  float mean = s1 * (1.f / EMB);
  float var = s2 * (1.f / EMB) - mean * mean;
  float rstd = rsqrtf(var + 1e-5f);
  if (tid < 32) xs[tid] = (lh[e0 + tid] - mean) * rstd * gv + bv;
  __syncthreads();
  float4 acc = {0.f, 0.f, 0.f, 0.f};
#pragma unroll
  for (int i = 0; i < 8; i++) {
    float x = xs[wid + i * 4];
    acc.x += x * w[i].x; acc.y += x * w[i].y; acc.z += x * w[i].z; acc.w += x * w[i].w;
  }
  red[wid][lane] = acc;
  __syncthreads();
  if (wid == 0) {
    float4 a0 = red[0][lane], a1 = red[1][lane], a2 = red[2][lane], a3 = red[3][lane];
    float rx = a0.x + a1.x + a2.x + a3.x;
    float ry = a0.y + a1.y + a2.y + a3.y;
    float rz = a0.z + a1.z + a2.z + a3.z;
    float rw = a0.w + a1.w + a2.w + a3.w;
    float* op = out + (size_t)j4 * 4;
    atomicAdd(op + 0, rx); atomicAdd(op + 1, ry);
    atomicAdd(op + 2, rz); atomicAdd(op + 3, rw);
  }
}

// attention partials for one (head, 64-key chunk); every block also writes its
// K/V chunk to the output cache (new slot S_PAST comes from qkv).
__global__ void attn_kv(const float* __restrict__ qkv, const float* __restrict__ pk,
                        const float* __restrict__ pv, const float* __restrict__ mask,
                        float* __restrict__ opk, float* __restrict__ opv,
                        float* __restrict__ part, int l) {
  int h = blockIdx.x >> 4, c = blockIdx.x & 15;
  int tid = threadIdx.x, lane = tid & 63, wid = tid >> 6;
  int sub = tid & 15, grp = tid >> 4;
  __shared__ float4 qs4[16];
  __shared__ float sc[64];
  __shared__ float4 redo[4][16];
  if (tid < 16) qs4[tid] = ((const float4*)(qkv + h * 64))[tid];
  __syncthreads();
  size_t base = ((size_t)(l * NH + h) * MAXS) * HD;
  const float4* K4 = (const float4*)(pk + base);
  const float4* V4 = (const float4*)(pv + base);
  float4* oK4 = (float4*)(opk + base);
  float4* oV4 = (float4*)(opv + base);
  int t0 = c * 64;
  float4 kreg[4];
#pragma unroll
  for (int i = 0; i < 4; i++) {
    int t = t0 + grp + i * 16;
    kreg[i] = (t == S_PAST) ? ((const float4*)(qkv + EMB + h * 64))[sub] : K4[(size_t)t * 16 + sub];
  }
#pragma unroll
  for (int i = 0; i < 4; i++) {
    int t = t0 + grp + i * 16;
    oK4[(size_t)t * 16 + sub] = kreg[i];
  }
  float4 q4 = qs4[sub];
#pragma unroll
  for (int i = 0; i < 4; i++) {
    int key = grp + i * 16;
    float p = q4.x * kreg[i].x + q4.y * kreg[i].y + q4.z * kreg[i].z + q4.w * kreg[i].w;
    p += __shfl_xor(p, 1); p += __shfl_xor(p, 2);
    p += __shfl_xor(p, 4); p += __shfl_xor(p, 8);
    if (sub == 0) sc[key] = p * 0.125f + (1.f - mask[t0 + key]) * (-1e9f);
  }
  __syncthreads();
  if (wid == 0) {
    float a = sc[lane];
    float m = a;
#pragma unroll
    for (int o = 32; o > 0; o >>= 1) m = fmaxf(m, __shfl_down(m, o));
    m = __shfl(m, 0);
    float ea = expf(a - m);
    sc[lane] = ea;
    float s = ea;
#pragma unroll
    for (int o = 32; o > 0; o >>= 1) s += __shfl_down(s, o);
    if (lane == 0) { part[(h * 16 + c) * 68 + 0] = m; part[(h * 16 + c) * 68 + 1] = s; }
  }
  __syncthreads();
  float4 vreg[4];
#pragma unroll
  for (int i = 0; i < 4; i++) {
    int t = t0 + grp + i * 16;
    vreg[i] = (t == S_PAST) ? ((const float4*)(qkv + 2 * EMB + h * 64))[sub] : V4[(size_t)t * 16 + sub];
  }
#pragma unroll
  for (int i = 0; i < 4; i++) {
    int t = t0 + grp + i * 16;
    oV4[(size_t)t * 16 + sub] = vreg[i];
  }
  float4 acc = {0.f, 0.f, 0.f, 0.f};
#pragma unroll
  for (int i = 0; i < 4; i++) {
    float w = sc[grp + i * 16];
    acc.x += w * vreg[i].x; acc.y += w * vreg[i].y; acc.z += w * vreg[i].z; acc.w += w * vreg[i].w;
  }
  acc.x += __shfl_xor(acc.x, 16); acc.y += __shfl_xor(acc.y, 16);
  acc.z += __shfl_xor(acc.z, 16); acc.w += __shfl_xor(acc.w, 16);
  acc.x += __shfl_xor(acc.x, 32); acc.y += __shfl_xor(acc.y, 32);
  acc.z += __shfl_xor(acc.z, 32); acc.w += __shfl_xor(acc.w, 32);
  if (lane < 16) redo[wid][lane] = acc;
  __syncthreads();
  if (tid < 16) {
    float4 a0 = redo[0][tid], a1 = redo[1][tid], a2 = redo[2][tid], a3 = redo[3][tid];
    float4 r;
    r.x = a0.x + a1.x + a2.x + a3.x;
    r.y = a0.y + a1.y + a2.y + a3.y;
    r.z = a0.z + a1.z + a2.z + a3.z;
    r.w = a0.w + a1.w + a2.w + a3.w;
    ((float4*)(part + (h * 16 + c) * 68 + 4))[tid] = r;
  }
}

// combine 16 chunk-partials (16-dim slice of head), then 16-row GEMV into h.
// Weight loads issued before the combine so combine latency hides under them.
__global__ void proj_attn(const float* __restrict__ part, const float* __restrict__ W,
                          const float* __restrict__ bias, const float* __restrict__ fc_b,
                          float* __restrict__ hout, float* __restrict__ wfc, int l) {
  int jb = blockIdx.x;           // 0..2 col tile
  int rt = blockIdx.y;           // 0..47 row tile (16 rows)
  int h = rt >> 2, esub = rt & 3;
  int tid = threadIdx.x, lane = tid & 63, wid = tid >> 6;
  __shared__ float xs[16];
  __shared__ float4 red[4][64];
  // issue weight loads first
  int j4 = jb * 64 + lane;
  const int N4 = EMB >> 2;
  int r0 = h * 64 + esub * 16;
  const float4* p = (const float4*)(W + (size_t)l * EMB * EMB) + (size_t)(r0 + wid) * N4 + j4;
  float4 w[4];
#pragma unroll
  for (int i = 0; i < 4; i++) w[i] = p[(size_t)(i * 4) * N4];
  // combine (independent of w loads)
  if (tid < 16) {
    float M = -1e30f;
#pragma unroll
    for (int q = 0; q < 16; q++) M = fmaxf(M, part[(h * 16 + q) * 68]);
    float T = 0.f, o = 0.f;
    int d = esub * 16 + tid;
#pragma unroll
    for (int q = 0; q < 16; q++) {
      float wq = expf(part[(h * 16 + q) * 68] - M);
      T += part[(h * 16 + q) * 68 + 1] * wq;
      o += part[(h * 16 + q) * 68 + 4 + d] * wq;
    }
    xs[tid] = o / T;
  }
  int bid = rt * 3 + jb;
  if (bid < 12) wfc[bid * 256 + tid] = fc_b[l * E4 + bid * 256 + tid];
  __syncthreads();
  float4 acc = {0.f, 0.f, 0.f, 0.f};
#pragma unroll
  for (int i = 0; i < 4; i++) {
    float x = xs[wid + i * 4];
    acc.x += x * w[i].x; acc.y += x * w[i].y; acc.z += x * w[i].z; acc.w += x * w[i].w;
  }
  red[wid][lane] = acc;
  __syncthreads();
  if (wid == 0) {
    float4 a0 = red[0][lane], a1 = red[1][lane], a2 = red[2][lane], a3 = red[3][lane];
    float rx = a0.x + a1.x + a2.x + a3.x;
    float ry = a0.y + a1.y + a2.y + a3.y;
    float rz = a0.z + a1.z + a2.z + a3.z;
    float rw = a0.w + a1.w + a2.w + a3.w;
    if (rt == 0) {
      const float* bp = bias + l * EMB + jb * 256 + lane * 4;
      rx += bp[0]; ry += bp[1]; rz += bp[2]; rw += bp[3];
    }
    float* op = hout + (size_t)jb * 256 + (size_t)lane * 4;
    atomicAdd(op + 0, rx); atomicAdd(op + 1, ry);
    atomicAdd(op + 2, rz); atomicAdd(op + 3, rw);
  }
}

// h[j] += sum_e gelu(fc[e]) * mlp_w[l][e][j]; 64 rows per block; seed next qkv.
// Weight loads issued before the gelu so activation latency hides under them.
__global__ void mlp_gemv4(const float* __restrict__ fcv, const float* __restrict__ W,
                          const float* __restrict__ bias, const float* __restrict__ attn_b,
                          float* __restrict__ hout, float* __restrict__ qkv, int l) {
  __shared__ float xs[64];
  __shared__ float4 red[4][64];
  int tid = threadIdx.x, lane = tid & 63, wid = tid >> 6;
  int e0 = blockIdx.y * 64;
  // issue weight loads first
  int j4 = blockIdx.x * 64 + lane;
  const int N4 = EMB >> 2;
  const float4* p = (const float4*)(W + (size_t)l * E4 * EMB) + (size_t)(e0 + wid) * N4 + j4;
  float4 w[16];
#pragma unroll
  for (int i = 0; i < 16; i++) w[i] = p[(size_t)(i * 4) * N4];
  if (tid < 64) {
    float x = fcv[e0 + tid];
    xs[tid] = 0.5f * x * (1.f + tanhf(0.7978845608028654f * (x + 0.044715f * x * x * x)));
  }
  int bid = blockIdx.y * 3 + blockIdx.x;
  if (l + 1 < NL && bid < 9) qkv[bid * 256 + tid] = attn_b[(l + 1) * E3 + bid * 256 + tid];
  __syncthreads();
  float4 acc = {0.f, 0.f, 0.f, 0.f};
#pragma unroll
  for (int i = 0; i < 16; i++) {
    float x = xs[wid + i * 4];
    acc.x += x * w[i].x; acc.y += x * w[i].y; acc.z += x * w[i].z; acc.w += x * w[i].w;
  }
  red[wid][lane] = acc;
  __syncthreads();
  if (wid == 0) {
    float4 a0 = red[0][lane], a1 = red[1][lane], a2 = red[2][lane], a3 = red[3][lane];
    float rx = a0.x + a1.x + a2.x + a3.x;
    float ry = a0.y + a1.y + a2.y + a3.y;
    float rz = a0.z + a1.z + a2.z + a3.z;
    float rw = a0.w + a1.w + a2.w + a3.w;
    if (blockIdx.y == 0) {
      const float* bp = bias + l * EMB + j4 * 4;
      rx += bp[0]; ry += bp[1]; rz += bp[2]; rw += bp[3];
    }
    float* op = hout + (size_t)j4 * 4;
    atomicAdd(op + 0, rx); atomicAdd(op + 1, ry);
    atomicAdd(op + 2, rz); atomicAdd(op + 3, rw);
  }
}

// final LN fused into logits: logits[v] = dot(LN(h), wte[v]); one wave per row
__global__ void logits_lnf(const float* __restrict__ hvec, const float* __restrict__ g,
                           const float* __restrict__ b, const float* __restrict__ wte,
                           float* __restrict__ out) {
  __shared__ float4 xs4[192];
  __shared__ float ra[4], rb[4];
  int tid = threadIdx.x, lane = tid & 63, wid = tid >> 6;
  // issue h loads, then wte row loads, then do stats
  float hv0 = hvec[tid], hv1 = hvec[tid + 256], hv2 = hvec[tid + 512];
  int v = blockIdx.x * 4 + wid;
  float4 a0 = {0,0,0,0}, a1 = {0,0,0,0}, a2 = {0,0,0,0};
  if (v < NV) {
    const float4* row = (const float4*)(wte + (size_t)v * EMB);
    a0 = row[lane]; a1 = row[lane + 64]; a2 = row[lane + 128];
  }
  float s1 = hv0 + hv1 + hv2;
  float s2 = hv0 * hv0 + hv1 * hv1 + hv2 * hv2;
  blockReduce2(s1, s2, ra, rb);
  float mean = s1 * (1.f / EMB);
  float var = s2 * (1.f / EMB) - mean * mean;
  float rstd = rsqrtf(var + 1e-5f);
  ((float*)xs4)[tid]       = (hv0 - mean) * rstd * g[tid]       + b[tid];
  ((float*)xs4)[tid + 256] = (hv1 - mean) * rstd * g[tid + 256] + b[tid + 256];
  ((float*)xs4)[tid + 512] = (hv2 - mean) * rstd * g[tid + 512] + b[tid + 512];
  __syncthreads();
  if (v >= NV) return;
  float4 x0 = xs4[lane], x1 = xs4[lane + 64], x2 = xs4[lane + 128];
  float acc = a0.x * x0.x + a0.y * x0.y + a0.z * x0.z + a0.w * x0.w
            + a1.x * x1.x + a1.y * x1.y + a1.z * x1.z + a1.w * x1.w
            + a2.x * x2.x + a2.y * x2.y + a2.z * x2.z + a2.w * x2.w;
#pragma unroll
  for (int o = 32; o > 0; o >>= 1) acc += __shfl_down(acc, o);
  if (lane == 0) out[v] = acc;
}

extern "C" void kernel_launch(void* const* d_in, const int* in_sizes, int n_in,
                              void* d_out, int out_size, void* d_ws, size_t ws_size,
                              hipStream_t stream) {
  const int* input_ids = (const int*)d_in[0];
  const float* past_key = (const float*)d_in[1];
  const float* past_value = (const float*)d_in[2];
  const float* mask = (const float*)d_in[4];
  const float* wte = (const float*)d_in[5];
  const float* wpe = (const float*)d_in[6];
  const float* ln1_g = (const float*)d_in[7];
  const float* ln1_b = (const float*)d_in[8];
  const float* attn_w = (const float*)d_in[9];
  const float* attn_b = (const float*)d_in[10];
  const float* proj_w = (const float*)d_in[11];
  const float* proj_b = (const float*)d_in[12];
  const float* ln2_g = (const float*)d_in[13];
  const float* ln2_b = (const float*)d_in[14];
  const float* fc_w = (const float*)d_in[15];
  const float* fc_b = (const float*)d_in[16];
  const float* mlp_w = (const float*)d_in[17];
  const float* mlp_b = (const float*)d_in[18];
  const float* lnf_g = (const float*)d_in[19];
  const float* lnf_b = (const float*)d_in[20];

  float* out = (float*)d_out;
  float* out_logits = out;
  float* out_pk = out + NV;
  float* out_pv = out_pk + (size_t)NL * NH * MAXS * HD;

  float* ws = (float*)d_ws;
  float* wh = ws + WS_H;
  float* wqkv = ws + WS_QKV;
  float* wfc = ws + WS_FC;
  float* wpart = ws + WS_PART;

  init_kernel<<<9, 256, 0, stream>>>(input_ids, wte, wpe, attn_b, wh, wqkv);

  for (int l = 0; l < NL; l++) {
    ln_gemv4<<<dim3(9, 24), 256, 0, stream>>>(wh, ln1_g, ln1_b, attn_w, wqkv, E3, l);
    attn_kv<<<192, 256, 0, stream>>>(wqkv, past_key, past_value, mask, out_pk, out_pv, wpart, l);
    proj_attn<<<dim3(3, 48), 256, 0, stream>>>(wpart, proj_w, proj_b, fc_b, wh, wfc, l);
    ln_gemv4<<<dim3(12, 24), 256, 0, stream>>>(wh, ln2_g, ln2_b, fc_w, wfc, E4, l);
    mlp_gemv4<<<dim3(3, 48), 256, 0, stream>>>(wfc, mlp_w, mlp_b, attn_b, wh, wqkv, l);
  }
  logits_lnf<<<12565, 256, 0, stream>>>(wh, lnf_g, lnf_b, wte, out_logits);
}